// Round 4
// baseline (146.371 us; speedup 1.0000x reference)
//
#include <hip/hip_runtime.h>

// WaveletFeatureExtractor: db4 wavedec (5 levels, symmetric pad) -> adaptive pool 128
// -> per-level 128x128 MLP (ReLU) -> fused 640->512 MLP (ReLU).
//
// Round 4 (dwt): 1024 thr/block (LDS 74.6KB -> 2 blocks/CU = 32 waves = 100% occ),
// D ping-pong so pooling of level k overlaps dwt of level k+1 (9 barriers -> 6),
// pooling via conflict-free b128 quad reads + <=2 LDS atomicAdds per quad
// (bucket-boundary classification: 2 cmps/element, torch overlap elem goes to
// both buckets). mlp unchanged from round 3.

#define BATCH   2048
#define SIGLEN  16384
#define N1      8195
#define N2      4101
#define N3      2054
#define N4      1030
#define N5      518
#define POOLP   128
#define COMB    640   // 5 * 128
#define OUTD    512
#define NTHR    1024

// Reversed db4 decomposition filters (reference flips filt[:, ::-1] -> correlation)
__device__ constexpr float LO[8] = {
     0.2303778133088965f,   0.7148465705529157f,   0.6308807679298589f,
    -0.027983769416859854f, -0.18703481171909309f,  0.030841381835560764f,
     0.0328830116668852f,  -0.010597401785069032f };
__device__ constexpr float HI[8] = {
    -0.010597401785069032f, -0.0328830116668852f,   0.030841381835560764f,
     0.18703481171909309f,  -0.027983769416859854f, -0.6308807679298589f,
     0.7148465705529157f,  -0.2303778133088965f };

// One LDS->LDS DWT level. N = src length, M = out length. Writes cA and cD.
template<int N, int M>
__device__ __forceinline__ void dwt_level_lds(const float* __restrict__ src,
                                              float* __restrict__ dstA,
                                              float* __restrict__ dstD,
                                              int tid) {
    for (int j0 = tid * 4; j0 < M; j0 += NTHR * 4) {
        if ((j0 >= 4) && (2 * j0 + 7 <= N - 1) && (j0 + 4 <= M)) {
            // fast path: 16-float window [2*j0-8, 2*j0+7] covers outputs j0..j0+3
            const float4* s4 = reinterpret_cast<const float4*>(src + 2 * j0 - 8);
            const float4 v0 = s4[0], v1 = s4[1], v2 = s4[2], v3 = s4[3];
            float w[16];
            w[0]=v0.x;  w[1]=v0.y;  w[2]=v0.z;  w[3]=v0.w;
            w[4]=v1.x;  w[5]=v1.y;  w[6]=v1.z;  w[7]=v1.w;
            w[8]=v2.x;  w[9]=v2.y;  w[10]=v2.z; w[11]=v2.w;
            w[12]=v3.x; w[13]=v3.y; w[14]=v3.z; w[15]=v3.w;
            float a[4], d[4];
#pragma unroll
            for (int k = 0; k < 4; ++k) {
                float aa = 0.f, dd = 0.f;
#pragma unroll
                for (int t = 0; t < 8; ++t) {
                    const float v = w[2 + 2 * k + t];
                    aa = fmaf(v, LO[t], aa);
                    dd = fmaf(v, HI[t], dd);
                }
                a[k] = aa; d[k] = dd;
            }
            *reinterpret_cast<float4*>(dstA + j0) = make_float4(a[0], a[1], a[2], a[3]);
            *reinterpret_cast<float4*>(dstD + j0) = make_float4(d[0], d[1], d[2], d[3]);
        } else {
            // boundary / tail path with symmetric folding
            for (int k = 0; k < 4; ++k) {
                const int j = j0 + k;
                if (j >= M) break;
                float aa = 0.f, dd = 0.f;
#pragma unroll
                for (int t = 0; t < 8; ++t) {
                    int idx = 2 * j - 6 + t;
                    idx = (idx < 0) ? (-1 - idx) : idx;
                    idx = (idx >= N) ? (2 * N - 1 - idx) : idx;
                    const float v = src[idx];
                    aa = fmaf(v, LO[t], aa);
                    dd = fmaf(v, HI[t], dd);
                }
                dstA[j] = aa;
                dstD[j] = dd;
            }
        }
    }
}

// Adaptive-pool scatter: thread reads 4 consecutive elements (b128, conflict-free),
// splits at the (single possible) bucket boundary, <=2 LDS atomicAdds.
// torch buckets: [floor(p*M/128), ceil((p+1)*M/128)) -> adjacent buckets overlap by
// <=1 element; that element (j in [sB,eB)) is summed into BOTH b0 and b0+1.
// Requires bucket width >= 4 (M >= 512), true for all bands here (min N5=518).
template<int M, int SLOT>
__device__ __forceinline__ void pool_quads(const float* __restrict__ buf,
                                           float* __restrict__ pacc, int tid) {
    constexpr int NQ = (M + 3) / 4;
    for (int q = tid; q < NQ; q += NTHR) {
        const int j0 = q * 4;
        const int cnt = (j0 + 4 <= M) ? 4 : (M - j0);
        float v0, v1, v2, v3;
        if (cnt == 4) {
            const float4 t = *reinterpret_cast<const float4*>(buf + j0);
            v0 = t.x; v1 = t.y; v2 = t.z; v3 = t.w;
        } else {
            v0 = buf[j0];
            v1 = (cnt > 1) ? buf[j0 + 1] : 0.f;
            v2 = (cnt > 2) ? buf[j0 + 2] : 0.f;
            v3 = 0.f;
        }
        const int b0   = (j0 * 128) / M;        // floor-bucket of first element
        const int prod = (b0 + 1) * M;
        const int sB   = prod >> 7;             // start of bucket b0+1
        const int eB   = (prod + 127) >> 7;     // end of bucket b0
        float s0 = 0.f, s1 = 0.f;
        s0 += (j0     < eB) ? v0 : 0.f;  s1 += (j0     >= sB) ? v0 : 0.f;
        s0 += (j0 + 1 < eB) ? v1 : 0.f;  s1 += (j0 + 1 >= sB) ? v1 : 0.f;
        s0 += (j0 + 2 < eB) ? v2 : 0.f;  s1 += (j0 + 2 >= sB) ? v2 : 0.f;
        s0 += (j0 + 3 < eB) ? v3 : 0.f;  s1 += (j0 + 3 >= sB) ? v3 : 0.f;
        atomicAdd(&pacc[SLOT * POOLP + b0], s0);
        if ((j0 + cnt > sB) && (b0 + 1 < POOLP))
            atomicAdd(&pacc[SLOT * POOLP + b0 + 1], s1);
    }
}

__global__ __launch_bounds__(NTHR, 8) void dwt_pool_kernel(const float* __restrict__ x,
                                                           float* __restrict__ pooled) {
    __shared__ __align__(16) float bufA[N1];    // cA1 / cA3 / cA5
    __shared__ __align__(16) float bufB[N2];    // cA2 / cA4
    __shared__ __align__(16) float bufD1[N2];   // cD2 / cD4
    __shared__ __align__(16) float bufD2[N3];   // cD3 / cD5
    __shared__ float pacc[COMB];                // pooled-sum accumulators

    const int tid = threadIdx.x;
    const int row = blockIdx.x;
    const float* __restrict__ xr = x + (size_t)row * SIGLEN;

    // P0: zero pacc + Level 1 global -> bufA (low-pass only; cD1 is dead)
    for (int i = tid; i < COMB; i += NTHR) pacc[i] = 0.f;
    for (int j0 = tid * 4; j0 < N1; j0 += NTHR * 4) {
        if ((j0 >= 4) && (2 * j0 + 7 <= SIGLEN - 1) && (j0 + 4 <= N1)) {
            const float4* s4 = reinterpret_cast<const float4*>(xr + 2 * j0 - 8);
            const float4 v0 = s4[0], v1 = s4[1], v2 = s4[2], v3 = s4[3];
            float w[16];
            w[0]=v0.x;  w[1]=v0.y;  w[2]=v0.z;  w[3]=v0.w;
            w[4]=v1.x;  w[5]=v1.y;  w[6]=v1.z;  w[7]=v1.w;
            w[8]=v2.x;  w[9]=v2.y;  w[10]=v2.z; w[11]=v2.w;
            w[12]=v3.x; w[13]=v3.y; w[14]=v3.z; w[15]=v3.w;
            float a[4];
#pragma unroll
            for (int k = 0; k < 4; ++k) {
                float aa = 0.f;
#pragma unroll
                for (int t = 0; t < 8; ++t) aa = fmaf(w[2 + 2 * k + t], LO[t], aa);
                a[k] = aa;
            }
            *reinterpret_cast<float4*>(bufA + j0) = make_float4(a[0], a[1], a[2], a[3]);
        } else {
            for (int k = 0; k < 4; ++k) {
                const int j = j0 + k;
                if (j >= N1) break;
                float aa = 0.f;
#pragma unroll
                for (int t = 0; t < 8; ++t) {
                    int idx = 2 * j - 6 + t;
                    idx = (idx < 0) ? (-1 - idx) : idx;
                    idx = (idx >= SIGLEN) ? (2 * SIGLEN - 1 - idx) : idx;
                    aa = fmaf(xr[idx], LO[t], aa);
                }
                bufA[j] = aa;
            }
        }
    }
    __syncthreads();

    // P1: L2: A(8195) -> B(cA2), D1(cD2)
    dwt_level_lds<N1, N2>(bufA, bufB, bufD1, tid);
    __syncthreads();

    // P2: L3: B(4101) -> A(cA3), D2(cD3)  ||  pool cD2 -> slot 4
    dwt_level_lds<N2, N3>(bufB, bufA, bufD2, tid);
    pool_quads<N2, 4>(bufD1, pacc, tid);
    __syncthreads();

    // P3: L4: A(2054) -> B(cA4), D1(cD4)  ||  pool cD3 -> slot 3
    dwt_level_lds<N3, N4>(bufA, bufB, bufD1, tid);
    pool_quads<N3, 3>(bufD2, pacc, tid);
    __syncthreads();

    // P4: L5: B(1030) -> A(cA5), D2(cD5)  ||  pool cD4 -> slot 2
    dwt_level_lds<N4, N5>(bufB, bufA, bufD2, tid);
    pool_quads<N4, 2>(bufD1, pacc, tid);
    __syncthreads();

    // P5: pool cA5 -> slot 0, cD5 -> slot 1
    pool_quads<N5, 0>(bufA, pacc, tid);
    pool_quads<N5, 1>(bufD2, pacc, tid);
    __syncthreads();

    // Finalize: divide bucket sums by bucket widths, write pooled[row][640]
    float* __restrict__ pr = pooled + (size_t)row * COMB;
    for (int c = tid; c < COMB; c += NTHR) {
        const int l = c >> 7, p = c & 127;
        const int n = (l <= 1) ? N5 : (l == 2 ? N4 : (l == 3 ? N3 : N2));
        const int s = (p * n) >> 7;
        const int e = ((p + 1) * n + 127) >> 7;
        pr[c] = pacc[c] / (float)(e - s);
    }
}

constexpr int MLP_R = 8;  // rows per block

__global__ __launch_bounds__(256) void mlp_kernel(const float* __restrict__ pooled,
                                                  const float* __restrict__ lw,  // [5][128][128]
                                                  const float* __restrict__ lb,  // [5][128]
                                                  const float* __restrict__ fw,  // [512][640]
                                                  const float* __restrict__ fb,  // [512]
                                                  float* __restrict__ out) {     // [B][512]
    __shared__ float sp[MLP_R][COMB];  // pooled tile
    __shared__ float sc[MLP_R][COMB];  // comb (post level-net ReLU) tile

    const int tid = threadIdx.x;
    const int r0 = blockIdx.x * MLP_R;

    for (int i = tid; i < MLP_R * COMB; i += 256) {
        (&sp[0][0])[i] = pooled[(size_t)r0 * COMB + i];
    }
    __syncthreads();

    // Level nets: comb[r][c] = relu(dot(sp[r][l*128..], lw[c][:]) + lb[c])
    for (int c = tid; c < COMB; c += 256) {
        const float* __restrict__ w = lw + (size_t)c * POOLP;
        const int lbase = (c >> 7) << 7;
        const float bias = lb[c];
        float acc[MLP_R];
#pragma unroll
        for (int r = 0; r < MLP_R; ++r) acc[r] = bias;
        for (int t = 0; t < POOLP; t += 4) {
            const float4 wv = *reinterpret_cast<const float4*>(w + t);
#pragma unroll
            for (int r = 0; r < MLP_R; ++r) {
                const float4 pv = *reinterpret_cast<const float4*>(&sp[r][lbase + t]);
                acc[r] += pv.x * wv.x + pv.y * wv.y + pv.z * wv.z + pv.w * wv.w;
            }
        }
#pragma unroll
        for (int r = 0; r < MLP_R; ++r) sc[r][c] = fmaxf(acc[r], 0.f);
    }
    __syncthreads();

    // Fusion: out[r][j] = relu(dot(sc[r][:], fw[j][:]) + fb[j])
    for (int j = tid; j < OUTD; j += 256) {
        const float* __restrict__ w = fw + (size_t)j * COMB;
        const float bias = fb[j];
        float acc[MLP_R];
#pragma unroll
        for (int r = 0; r < MLP_R; ++r) acc[r] = bias;
        for (int t = 0; t < COMB; t += 4) {
            const float4 wv = *reinterpret_cast<const float4*>(w + t);
#pragma unroll
            for (int r = 0; r < MLP_R; ++r) {
                const float4 cv = *reinterpret_cast<const float4*>(&sc[r][t]);
                acc[r] += cv.x * wv.x + cv.y * wv.y + cv.z * wv.z + cv.w * wv.w;
            }
        }
#pragma unroll
        for (int r = 0; r < MLP_R; ++r) {
            out[(size_t)(r0 + r) * OUTD + j] = fmaxf(acc[r], 0.f);
        }
    }
}

extern "C" void kernel_launch(void* const* d_in, const int* in_sizes, int n_in,
                              void* d_out, int out_size, void* d_ws, size_t ws_size,
                              hipStream_t stream) {
    const float* x  = (const float*)d_in[0];  // [2048][16384]
    const float* lw = (const float*)d_in[1];  // [5][128][128]
    const float* lb = (const float*)d_in[2];  // [5][128]
    const float* fw = (const float*)d_in[3];  // [512][640]
    const float* fb = (const float*)d_in[4];  // [512]
    float* out = (float*)d_out;               // [2048][512]

    float* pooled = (float*)d_ws;             // [2048][640] fp32 = 5.24 MB

    dwt_pool_kernel<<<BATCH, NTHR, 0, stream>>>(x, pooled);
    mlp_kernel<<<BATCH / MLP_R, 256, 0, stream>>>(pooled, lw, lb, fw, fb, out);
}

// Round 6
// 123.577 us; speedup vs baseline: 1.1845x; 1.1845x over previous
//
#include <hip/hip_runtime.h>

// WaveletFeatureExtractor: db4 wavedec (5 levels, symmetric pad) -> adaptive pool 128
// -> per-level 128x128 MLP (ReLU) -> fused 640->512 MLP (ReLU).
//
// Round 6 = round 5 with the h2 type fixed (__fp16 ext_vector(2), matching
// cvt_pkrtz / fdot2 builtin signatures).
//  dwt: 512 thr, lb(512,4) (ILP > occupancy for this kernel; lb(1024,8) forced
//  VGPR=20 and regressed) + pool/dwt phase overlap (D ping-pong, shfl pool, no
//  atomics) + XOR-swizzled LDS (i ^= ((i>>5)&7)<<2 on dword idx): kills the
//  16-way bank conflict of 32B-lane-stride ds_read_b128 window reads.
//  mlp: packed-f16 v_dot2_f32_f16 (halves VALU instrs + LDS bytes), 512 thr.

#define BATCH   2048
#define SIGLEN  16384
#define N1      8195
#define N2      4101
#define N3      2054
#define N4      1030
#define N5      518
#define POOLP   128
#define COMB    640   // 5 * 128
#define OUTD    512
#define NTHR    512

// LDS swizzle on dword index: XOR bits [4:2] with bits [7:5]. Bijective within
// each 32-dword block; preserves 16B (float4) alignment. Buffers padded to 32.
#define SWZ(i) ((i) ^ ((((i) >> 5) & 7) << 2))

// Reversed db4 decomposition filters (reference flips filt[:, ::-1] -> correlation)
__device__ constexpr float LO[8] = {
     0.2303778133088965f,   0.7148465705529157f,   0.6308807679298589f,
    -0.027983769416859854f, -0.18703481171909309f,  0.030841381835560764f,
     0.0328830116668852f,  -0.010597401785069032f };
__device__ constexpr float HI[8] = {
    -0.010597401785069032f, -0.0328830116668852f,   0.030841381835560764f,
     0.18703481171909309f,  -0.027983769416859854f, -0.6308807679298589f,
     0.7148465705529157f,  -0.2303778133088965f };

// One LDS->LDS DWT level (swizzled src/dst). N = src length, M = out length.
template<int N, int M>
__device__ __forceinline__ void dwt_level_lds(const float* __restrict__ src,
                                              float* __restrict__ dstA,
                                              float* __restrict__ dstD,
                                              int tid) {
    for (int j0 = tid * 4; j0 < M; j0 += NTHR * 4) {
        if ((j0 >= 4) && (2 * j0 + 7 <= N - 1) && (j0 + 4 <= M)) {
            const int rb = 2 * j0 - 8;   // mult of 8
            const float4 v0 = *reinterpret_cast<const float4*>(src + SWZ(rb));
            const float4 v1 = *reinterpret_cast<const float4*>(src + SWZ(rb + 4));
            const float4 v2 = *reinterpret_cast<const float4*>(src + SWZ(rb + 8));
            const float4 v3 = *reinterpret_cast<const float4*>(src + SWZ(rb + 12));
            float w[16];
            w[0]=v0.x;  w[1]=v0.y;  w[2]=v0.z;  w[3]=v0.w;
            w[4]=v1.x;  w[5]=v1.y;  w[6]=v1.z;  w[7]=v1.w;
            w[8]=v2.x;  w[9]=v2.y;  w[10]=v2.z; w[11]=v2.w;
            w[12]=v3.x; w[13]=v3.y; w[14]=v3.z; w[15]=v3.w;
            float a[4], d[4];
#pragma unroll
            for (int k = 0; k < 4; ++k) {
                float aa = 0.f, dd = 0.f;
#pragma unroll
                for (int t = 0; t < 8; ++t) {
                    const float v = w[2 + 2 * k + t];
                    aa = fmaf(v, LO[t], aa);
                    dd = fmaf(v, HI[t], dd);
                }
                a[k] = aa; d[k] = dd;
            }
            *reinterpret_cast<float4*>(dstA + SWZ(j0)) = make_float4(a[0], a[1], a[2], a[3]);
            *reinterpret_cast<float4*>(dstD + SWZ(j0)) = make_float4(d[0], d[1], d[2], d[3]);
        } else {
            for (int k = 0; k < 4; ++k) {
                const int j = j0 + k;
                if (j >= M) break;
                float aa = 0.f, dd = 0.f;
#pragma unroll
                for (int t = 0; t < 8; ++t) {
                    int idx = 2 * j - 6 + t;
                    idx = (idx < 0) ? (-1 - idx) : idx;
                    idx = (idx >= N) ? (2 * N - 1 - idx) : idx;
                    const float v = src[SWZ(idx)];
                    aa = fmaf(v, LO[t], aa);
                    dd = fmaf(v, HI[t], dd);
                }
                dstA[SWZ(j)] = aa;
                dstD[SWZ(j)] = dd;
            }
        }
    }
}

// Contention-free adaptive pool over a swizzled LDS band: 4 threads per bucket,
// stride-4 partials, 2x shfl_xor combine, lane 0 writes the mean to global.
template<int M, int SLOT>
__device__ __forceinline__ void pool_band(const float* __restrict__ buf,
                                          float* __restrict__ pr, int tid) {
    const int p = tid >> 2, sub = tid & 3;
    const int s = (p * M) >> 7;
    const int e = ((p + 1) * M + 127) >> 7;
    float acc = 0.f;
    for (int t = s + sub; t < e; t += 4) acc += buf[SWZ(t)];
    acc += __shfl_xor(acc, 1);
    acc += __shfl_xor(acc, 2);
    if (sub == 0) pr[SLOT * POOLP + p] = acc / (float)(e - s);
}

__global__ __launch_bounds__(NTHR, 4) void dwt_pool_kernel(const float* __restrict__ x,
                                                           float* __restrict__ pooled) {
    // padded to multiples of 32 dwords for the swizzle
    __shared__ __align__(16) float bufA[8224];    // cA1 / cA3 / cA5
    __shared__ __align__(16) float bufB[4128];    // cA2 / cA4
    __shared__ __align__(16) float bufD1[4128];   // cD2 / cD4
    __shared__ __align__(16) float bufD2[2080];   // cD3 / cD5

    const int tid = threadIdx.x;
    const int row = blockIdx.x;
    const float* __restrict__ xr = x + (size_t)row * SIGLEN;
    float* __restrict__ pr = pooled + (size_t)row * COMB;

    // P0: Level 1 global -> bufA (low-pass only; cD1 is dead in the forward)
    for (int j0 = tid * 4; j0 < N1; j0 += NTHR * 4) {
        if ((j0 >= 4) && (2 * j0 + 7 <= SIGLEN - 1) && (j0 + 4 <= N1)) {
            const float4* s4 = reinterpret_cast<const float4*>(xr + 2 * j0 - 8);
            const float4 v0 = s4[0], v1 = s4[1], v2 = s4[2], v3 = s4[3];
            float w[16];
            w[0]=v0.x;  w[1]=v0.y;  w[2]=v0.z;  w[3]=v0.w;
            w[4]=v1.x;  w[5]=v1.y;  w[6]=v1.z;  w[7]=v1.w;
            w[8]=v2.x;  w[9]=v2.y;  w[10]=v2.z; w[11]=v2.w;
            w[12]=v3.x; w[13]=v3.y; w[14]=v3.z; w[15]=v3.w;
            float a[4];
#pragma unroll
            for (int k = 0; k < 4; ++k) {
                float aa = 0.f;
#pragma unroll
                for (int t = 0; t < 8; ++t) aa = fmaf(w[2 + 2 * k + t], LO[t], aa);
                a[k] = aa;
            }
            *reinterpret_cast<float4*>(bufA + SWZ(j0)) = make_float4(a[0], a[1], a[2], a[3]);
        } else {
            for (int k = 0; k < 4; ++k) {
                const int j = j0 + k;
                if (j >= N1) break;
                float aa = 0.f;
#pragma unroll
                for (int t = 0; t < 8; ++t) {
                    int idx = 2 * j - 6 + t;
                    idx = (idx < 0) ? (-1 - idx) : idx;
                    idx = (idx >= SIGLEN) ? (2 * SIGLEN - 1 - idx) : idx;
                    aa = fmaf(xr[idx], LO[t], aa);
                }
                bufA[SWZ(j)] = aa;
            }
        }
    }
    __syncthreads();

    // P1: L2: A(8195) -> B(cA2), D1(cD2)
    dwt_level_lds<N1, N2>(bufA, bufB, bufD1, tid);
    __syncthreads();

    // P2: L3: B -> A(cA3), D2(cD3)   || pool cD2 -> slot 4
    dwt_level_lds<N2, N3>(bufB, bufA, bufD2, tid);
    pool_band<N2, 4>(bufD1, pr, tid);
    __syncthreads();

    // P3: L4: A -> B(cA4), D1(cD4)   || pool cD3 -> slot 3
    dwt_level_lds<N3, N4>(bufA, bufB, bufD1, tid);
    pool_band<N3, 3>(bufD2, pr, tid);
    __syncthreads();

    // P4: L5: B -> A(cA5), D2(cD5)   || pool cD4 -> slot 2
    dwt_level_lds<N4, N5>(bufB, bufA, bufD2, tid);
    pool_band<N4, 2>(bufD1, pr, tid);
    __syncthreads();

    // P5: pool cA5 -> slot 0, cD5 -> slot 1
    pool_band<N5, 0>(bufA, pr, tid);
    pool_band<N5, 1>(bufD2, pr, tid);
}

// ---------------- MLP: packed f16 dot2 ----------------

typedef __fp16 h2 __attribute__((ext_vector_type(2)));

constexpr int MLP_R = 8;  // rows per block

__global__ __launch_bounds__(512) void mlp_kernel(const float* __restrict__ pooled,
                                                  const float* __restrict__ lw,  // [5][128][128]
                                                  const float* __restrict__ lb,  // [5][128]
                                                  const float* __restrict__ fw,  // [512][640]
                                                  const float* __restrict__ fb,  // [512]
                                                  float* __restrict__ out) {     // [B][512]
    __shared__ h2 sph[MLP_R][COMB / 2];  // pooled tile, f16-packed (8 x 320)
    __shared__ h2 sch[MLP_R][COMB / 2];  // comb tile, f16-packed

    const int tid = threadIdx.x;
    const int r0 = blockIdx.x * MLP_R;

    // Load pooled tile, convert f32 -> packed f16
    const float2* __restrict__ srcp = reinterpret_cast<const float2*>(pooled + (size_t)r0 * COMB);
    for (int i = tid; i < MLP_R * (COMB / 2); i += 512) {
        const float2 v = srcp[i];
        (&sph[0][0])[i] = __builtin_amdgcn_cvt_pkrtz(v.x, v.y);
    }
    __syncthreads();

    // Level nets: comb[r][c] = relu(dot_f16(sph[r][l*64..], lw[c]) + lb[c])
    for (int c = tid; c < COMB; c += 512) {
        const float* __restrict__ w = lw + (size_t)c * POOLP;
        const int lb2 = (c >> 7) * (POOLP / 2);
        const float bias = lb[c];
        float acc[MLP_R];
#pragma unroll
        for (int r = 0; r < MLP_R; ++r) acc[r] = bias;
        for (int t2 = 0; t2 < POOLP / 2; t2 += 4) {   // 8 taps per iter
            const float4 wa = *reinterpret_cast<const float4*>(w + t2 * 2);
            const float4 wb = *reinterpret_cast<const float4*>(w + t2 * 2 + 4);
            const h2 w0 = __builtin_amdgcn_cvt_pkrtz(wa.x, wa.y);
            const h2 w1 = __builtin_amdgcn_cvt_pkrtz(wa.z, wa.w);
            const h2 w2 = __builtin_amdgcn_cvt_pkrtz(wb.x, wb.y);
            const h2 w3 = __builtin_amdgcn_cvt_pkrtz(wb.z, wb.w);
#pragma unroll
            for (int r = 0; r < MLP_R; ++r) {
                const float4 raw = *reinterpret_cast<const float4*>(&sph[r][lb2 + t2]);
                acc[r] = __builtin_amdgcn_fdot2(__builtin_bit_cast(h2, raw.x), w0, acc[r], false);
                acc[r] = __builtin_amdgcn_fdot2(__builtin_bit_cast(h2, raw.y), w1, acc[r], false);
                acc[r] = __builtin_amdgcn_fdot2(__builtin_bit_cast(h2, raw.z), w2, acc[r], false);
                acc[r] = __builtin_amdgcn_fdot2(__builtin_bit_cast(h2, raw.w), w3, acc[r], false);
            }
        }
        __fp16* __restrict__ schf = reinterpret_cast<__fp16*>(&sch[0][0]);
#pragma unroll
        for (int r = 0; r < MLP_R; ++r) {
            schf[r * COMB + c] = (__fp16)fmaxf(acc[r], 0.f);
        }
    }
    __syncthreads();

    // Fusion: out[r][j] = relu(dot_f16(sch[r][:], fw[j]) + fb[j]);  j = tid (512)
    {
        const int j = tid;
        const float* __restrict__ w = fw + (size_t)j * COMB;
        const float bias = fb[j];
        float acc[MLP_R];
#pragma unroll
        for (int r = 0; r < MLP_R; ++r) acc[r] = bias;
        for (int t2 = 0; t2 < COMB / 2; t2 += 4) {    // 8 taps per iter
            const float4 wa = *reinterpret_cast<const float4*>(w + t2 * 2);
            const float4 wb = *reinterpret_cast<const float4*>(w + t2 * 2 + 4);
            const h2 w0 = __builtin_amdgcn_cvt_pkrtz(wa.x, wa.y);
            const h2 w1 = __builtin_amdgcn_cvt_pkrtz(wa.z, wa.w);
            const h2 w2 = __builtin_amdgcn_cvt_pkrtz(wb.x, wb.y);
            const h2 w3 = __builtin_amdgcn_cvt_pkrtz(wb.z, wb.w);
#pragma unroll
            for (int r = 0; r < MLP_R; ++r) {
                const float4 raw = *reinterpret_cast<const float4*>(&sch[r][t2]);
                acc[r] = __builtin_amdgcn_fdot2(__builtin_bit_cast(h2, raw.x), w0, acc[r], false);
                acc[r] = __builtin_amdgcn_fdot2(__builtin_bit_cast(h2, raw.y), w1, acc[r], false);
                acc[r] = __builtin_amdgcn_fdot2(__builtin_bit_cast(h2, raw.z), w2, acc[r], false);
                acc[r] = __builtin_amdgcn_fdot2(__builtin_bit_cast(h2, raw.w), w3, acc[r], false);
            }
        }
#pragma unroll
        for (int r = 0; r < MLP_R; ++r) {
            out[(size_t)(r0 + r) * OUTD + j] = fmaxf(acc[r], 0.f);
        }
    }
}

extern "C" void kernel_launch(void* const* d_in, const int* in_sizes, int n_in,
                              void* d_out, int out_size, void* d_ws, size_t ws_size,
                              hipStream_t stream) {
    const float* x  = (const float*)d_in[0];  // [2048][16384]
    const float* lw = (const float*)d_in[1];  // [5][128][128]
    const float* lb = (const float*)d_in[2];  // [5][128]
    const float* fw = (const float*)d_in[3];  // [512][640]
    const float* fb = (const float*)d_in[4];  // [512]
    float* out = (float*)d_out;               // [2048][512]

    float* pooled = (float*)d_ws;             // [2048][640] fp32 = 5.24 MB

    dwt_pool_kernel<<<BATCH, NTHR, 0, stream>>>(x, pooled);
    mlp_kernel<<<BATCH / MLP_R, 512, 0, stream>>>(pooled, lw, lb, fw, fb, out);
}